// Round 1
// baseline (805.976 us; speedup 1.0000x reference)
//
#include <hip/hip_runtime.h>
#include <hip/hip_bf16.h>

#define N_NODES 10000
#define CAP 64            // max nnz per row we store (Binomial(10000,0.002) tail past 64 ~ 1e-15)

// ---------------- workspace layout (element offsets, 4B units) ----------------
// all offsets divisible by 4 -> 16B aligned
#define OFF_CNT     0                         // int[10000]
#define OFF_COLSUM  10000                     // float[64]
#define OFF_COLS    10064                     // int[10000*64]
#define OFF_VALS    650064                    // float[10000*64]
#define OFF_SSRC    1290064                   // float[10000]
#define OFF_SDST    1300064                   // float[10000]
#define OFF_P       1310064                   // float[10000*64]
#define OFF_Q       1950064
#define OFF_R1      2590064
#define OFF_T1      3230064
#define OFF_U       3870064
#define OFF_V       4510064
// total = 5150064 elems = 20.6 MB

// ---------------- kernels ----------------

__global__ void zero_kernel(int* p, int n) {
    int i = blockIdx.x * blockDim.x + threadIdx.x;
    if (i < n) p[i] = 0;
}

// Extract nonzeros of dense adj into per-row lists. grid = dim3(3, N), block 256.
__global__ void sparsify_kernel(const float4* __restrict__ adj4,
                                int* __restrict__ cnt,
                                int* __restrict__ cols,
                                float* __restrict__ vals) {
    const int row = blockIdx.y;
    const int row4 = N_NODES / 4;    // 2500 float4 per row
    int base = blockIdx.x * 1024 + threadIdx.x;
    #pragma unroll
    for (int it = 0; it < 4; ++it) {
        int idx = base + it * 256;
        if (idx < row4) {
            float4 v = adj4[(size_t)row * row4 + idx];
            float vv[4] = {v.x, v.y, v.z, v.w};
            #pragma unroll
            for (int l = 0; l < 4; ++l) {
                if (vv[l] != 0.0f) {
                    int pos = atomicAdd(&cnt[row], 1);
                    if (pos < CAP) {
                        cols[(size_t)row * CAP + pos] = idx * 4 + l;
                        vals[(size_t)row * CAP + pos] = vv[l];
                    }
                }
            }
        }
    }
}

// out[N,64] = x[N,128] @ W[128,64].  block 256 (4 rows), grid 2500.
__global__ void gemm128_kernel(const float* __restrict__ x,
                               const float* __restrict__ W,
                               float* __restrict__ out) {
    __shared__ float Ws[128 * 64];
    __shared__ float xs[4 * 128];
    int tid = threadIdx.x;
    for (int i = tid; i < 128 * 64; i += 256) Ws[i] = W[i];
    int row0 = blockIdx.x * 4;
    for (int i = tid; i < 4 * 128; i += 256)
        xs[i] = x[(size_t)row0 * 128 + i];
    __syncthreads();
    int r = tid >> 6, f = tid & 63;
    float acc = 0.0f;
    #pragma unroll 8
    for (int k = 0; k < 128; ++k) acc += xs[r * 128 + k] * Ws[k * 64 + f];
    out[(size_t)(row0 + r) * 64 + f] = acc;
}

// out[N,64] = act(in[N,64] @ W[64,64] + b).  block 256 (4 rows), grid 2500.
__global__ void gemm64_kernel(const float* __restrict__ in,
                              const float* __restrict__ W,
                              const float* __restrict__ b,
                              float* __restrict__ out,
                              int relu_flag) {
    __shared__ float Ws[64 * 64];
    __shared__ float xs[4 * 64];
    int tid = threadIdx.x;
    for (int i = tid; i < 64 * 64; i += 256) Ws[i] = W[i];
    int row0 = blockIdx.x * 4;
    xs[tid] = in[(size_t)row0 * 64 + tid];
    __syncthreads();
    int r = tid >> 6, f = tid & 63;
    float acc = b ? b[f] : 0.0f;
    #pragma unroll
    for (int k = 0; k < 64; ++k) acc += xs[r * 64 + k] * Ws[k * 64 + f];
    if (relu_flag) acc = fmaxf(acc, 0.0f);
    out[(size_t)(row0 + r) * 64 + f] = acc;
}

// out[row,f] = relu( sum_p vals[row,p]*in[cols[row,p],f] + b[f] )
__global__ void spmm_kernel(const int* __restrict__ cnt,
                            const int* __restrict__ cols,
                            const float* __restrict__ vals,
                            const float* __restrict__ in,
                            const float* __restrict__ b,
                            float* __restrict__ out) {
    int tid = threadIdx.x;
    int row = blockIdx.x * 4 + (tid >> 6);
    int f = tid & 63;
    int c = min(cnt[row], CAP);
    const int* cp = cols + (size_t)row * CAP;
    const float* vp = vals + (size_t)row * CAP;
    float acc = 0.0f;
    for (int p = 0; p < c; ++p)
        acc += vp[p] * in[(size_t)cp[p] * 64 + f];
    acc += b[f];
    out[(size_t)row * 64 + f] = fmaxf(acc, 0.0f);
}

// s_src[i] = ro[i]·a[0:64] + rt[i]·a[64:128]; s_dst[i] = ro[i]·a[128:192] + rt[i]·a[192:256]
__global__ void score_kernel(const float* __restrict__ ro,
                             const float* __restrict__ rt,
                             const float* __restrict__ a,
                             float* __restrict__ s_src,
                             float* __restrict__ s_dst) {
    int tid = threadIdx.x;
    int row = blockIdx.x * 4 + (tid >> 6);
    int f = tid & 63;
    float vo = ro[(size_t)row * 64 + f], vt = rt[(size_t)row * 64 + f];
    float ps = vo * a[f] + vt * a[64 + f];
    float pd = vo * a[128 + f] + vt * a[192 + f];
    #pragma unroll
    for (int off = 32; off >= 1; off >>= 1) {
        ps += __shfl_xor(ps, off, 64);
        pd += __shfl_xor(pd, off, 64);
    }
    if (f == 0) { s_src[row] = ps; s_dst[row] = pd; }
}

// colsum[f] = sum_i rt[i,f].  grid 40 blocks x 250 rows each.
__global__ void colsum_kernel(const float* __restrict__ rt, float* __restrict__ colsum) {
    int tid = threadIdx.x;
    int f = tid & 63, w = tid >> 6;
    int start = blockIdx.x * 250;
    float acc = 0.0f;
    for (int i = start + w; i < start + 250; i += 4)
        acc += rt[(size_t)i * 64 + f];
    atomicAdd(&colsum[f], acc);
}

// Sparse-aware full-dense-row softmax attention:
// rep_out[i] = (sum_{j in nnz}(e_ij - e^-m)*rt[j] + e^-m * colsum) / Z + ro[i]
__global__ void attn_kernel(const int* __restrict__ cnt,
                            const int* __restrict__ cols,
                            const float* __restrict__ s_src,
                            const float* __restrict__ s_dst,
                            const float* __restrict__ colsum,
                            const float* __restrict__ ro,
                            const float* __restrict__ rt,
                            float* __restrict__ rep_out) {
    int tid = threadIdx.x;
    int row = blockIdx.x * 4 + (tid >> 6);
    int lane = tid & 63;
    int c = min(cnt[row], CAP);
    const int* cp = cols + (size_t)row * CAP;
    float ssrc = s_src[row];
    float s_l = -1e30f;
    if (lane < c) s_l = ssrc + s_dst[cp[lane]];
    float m = s_l;
    #pragma unroll
    for (int off = 32; off >= 1; off >>= 1) m = fmaxf(m, __shfl_xor(m, off, 64));
    m = fmaxf(m, 0.0f);   // the (N - nnz) zero entries participate in the row max
    float e_l = (lane < c) ? expf(s_l - m) : 0.0f;
    float Z = e_l;
    #pragma unroll
    for (int off = 32; off >= 1; off >>= 1) Z += __shfl_xor(Z, off, 64);
    float em = expf(-m);
    Z += (float)(N_NODES - c) * em;
    float acc = 0.0f;
    for (int p = 0; p < c; ++p) {
        float ep = __shfl(e_l, p, 64);
        int colp = cp[p];
        acc += (ep - em) * rt[(size_t)colp * 64 + lane];
    }
    float outv = (acc + em * colsum[lane]) / Z + ro[(size_t)row * 64 + lane];
    rep_out[(size_t)row * 64 + lane] = outv;
}

// treatment = sigmoid(h @ Wpp2[64,2] + bpp2[2])
__global__ void treat_kernel(const float* __restrict__ h,
                             const float* __restrict__ Wpp2,
                             const float* __restrict__ bpp2,
                             float* __restrict__ out_treat) {
    int tid = threadIdx.x;
    int row = blockIdx.x * 4 + (tid >> 6);
    int k = tid & 63;
    float hv = h[(size_t)row * 64 + k];
    float p0 = hv * Wpp2[k * 2 + 0];
    float p1 = hv * Wpp2[k * 2 + 1];
    #pragma unroll
    for (int off = 32; off >= 1; off >>= 1) {
        p0 += __shfl_xor(p0, off, 64);
        p1 += __shfl_xor(p1, off, 64);
    }
    if (k == 0) {
        out_treat[(size_t)row * 2 + 0] = 1.0f / (1.0f + expf(-(p0 + bpp2[0])));
        out_treat[(size_t)row * 2 + 1] = 1.0f / (1.0f + expf(-(p1 + bpp2[1])));
    }
}

// y[i] = t[i]>0 ? h1[i]·Wo1 + bo1 : h0[i]·Wo0 + bo0
__global__ void y_kernel(const float* __restrict__ h0, const float* __restrict__ h1,
                         const float* __restrict__ Wo0, const float* __restrict__ bo0,
                         const float* __restrict__ Wo1, const float* __restrict__ bo1,
                         const int* __restrict__ t, float* __restrict__ y) {
    int tid = threadIdx.x;
    int row = blockIdx.x * 4 + (tid >> 6);
    int k = tid & 63;
    float p0 = h0[(size_t)row * 64 + k] * Wo0[k];
    float p1 = h1[(size_t)row * 64 + k] * Wo1[k];
    #pragma unroll
    for (int off = 32; off >= 1; off >>= 1) {
        p0 += __shfl_xor(p0, off, 64);
        p1 += __shfl_xor(p1, off, 64);
    }
    if (k == 0) {
        float y0 = p0 + bo0[0];
        float y1 = p1 + bo1[0];
        y[row] = (t[row] > 0) ? y1 : y0;
    }
}

// ---------------- launch ----------------

extern "C" void kernel_launch(void* const* d_in, const int* in_sizes, int n_in,
                              void* d_out, int out_size, void* d_ws, size_t ws_size,
                              hipStream_t stream) {
    const float* x    = (const float*)d_in[0];
    const float* adj  = (const float*)d_in[1];
    const int*   t    = (const int*)d_in[2];
    const float* Wg0  = (const float*)d_in[3];
    const float* bg0  = (const float*)d_in[4];
    const float* Wg1  = (const float*)d_in[5];
    const float* bg1  = (const float*)d_in[6];
    const float* Wt0  = (const float*)d_in[7];
    const float* bt0  = (const float*)d_in[8];
    const float* Wt1  = (const float*)d_in[9];
    const float* bt1  = (const float*)d_in[10];
    const float* W000 = (const float*)d_in[11];
    const float* b000 = (const float*)d_in[12];
    const float* W001 = (const float*)d_in[13];
    const float* b001 = (const float*)d_in[14];
    const float* W100 = (const float*)d_in[15];
    const float* b100 = (const float*)d_in[16];
    const float* W101 = (const float*)d_in[17];
    const float* b101 = (const float*)d_in[18];
    const float* Wo0  = (const float*)d_in[19];
    const float* bo0  = (const float*)d_in[20];
    const float* Wo1  = (const float*)d_in[21];
    const float* bo1  = (const float*)d_in[22];
    const float* Wpp  = (const float*)d_in[23];
    const float* bpp  = (const float*)d_in[24];
    const float* Wpp2 = (const float*)d_in[25];
    const float* bpp2 = (const float*)d_in[26];
    const float* a    = (const float*)d_in[27];

    float* ws = (float*)d_ws;
    int*   cnt    = (int*)(ws + OFF_CNT);
    float* colsum = ws + OFF_COLSUM;
    int*   cols   = (int*)(ws + OFF_COLS);
    float* vals   = ws + OFF_VALS;
    float* s_src  = ws + OFF_SSRC;
    float* s_dst  = ws + OFF_SDST;
    float* P      = ws + OFF_P;
    float* Q      = ws + OFF_Q;
    float* R1     = ws + OFF_R1;
    float* T1     = ws + OFF_T1;
    float* U      = ws + OFF_U;
    float* V      = ws + OFF_V;

    float* out_y    = (float*)d_out;                    // [N]
    float* rep_out  = (float*)d_out + N_NODES;          // [N,64]
    float* out_trt  = (float*)d_out + N_NODES + N_NODES * 64;  // [N,2]

    const int RB = N_NODES / 4;   // 2500 blocks of 4 rows

    // 0) zero cnt + colsum (contiguous 10064 ints)
    zero_kernel<<<(10064 + 255) / 256, 256, 0, stream>>>((int*)d_ws, 10064);

    // 1) sparsify adj (400 MB streaming pass)
    sparsify_kernel<<<dim3(3, N_NODES), 256, 0, stream>>>((const float4*)adj, cnt, cols, vals);

    // 2) layer-1 GCN: P = x@Wg0 ; Q = x@Wt0 ; spmm+bias+relu
    gemm128_kernel<<<RB, 256, 0, stream>>>(x, Wg0, P);
    gemm128_kernel<<<RB, 256, 0, stream>>>(x, Wt0, Q);
    spmm_kernel<<<RB, 256, 0, stream>>>(cnt, cols, vals, P, bg0, R1);
    spmm_kernel<<<RB, 256, 0, stream>>>(cnt, cols, vals, Q, bt0, T1);

    // 3) layer-2 GCN
    gemm64_kernel<<<RB, 256, 0, stream>>>(R1, Wg1, nullptr, P, 0);
    gemm64_kernel<<<RB, 256, 0, stream>>>(T1, Wt1, nullptr, Q, 0);
    spmm_kernel<<<RB, 256, 0, stream>>>(cnt, cols, vals, P, bg1, R1);  // final rep_o
    spmm_kernel<<<RB, 256, 0, stream>>>(cnt, cols, vals, Q, bt1, T1);  // final rep_t

    // 4) attention scores + colsum
    score_kernel<<<RB, 256, 0, stream>>>(R1, T1, a, s_src, s_dst);
    colsum_kernel<<<40, 256, 0, stream>>>(T1, colsum);

    // 5) attention -> rep_out (written directly into d_out)
    attn_kernel<<<RB, 256, 0, stream>>>(cnt, cols, s_src, s_dst, colsum, R1, T1, rep_out);

    // 6) treatment head: P = T1@Wpp + bpp (no act); sigmoid head
    gemm64_kernel<<<RB, 256, 0, stream>>>(T1, Wpp, bpp, P, 0);
    treat_kernel<<<RB, 256, 0, stream>>>(P, Wpp2, bpp2, out_trt);

    // 7) outcome heads
    gemm64_kernel<<<RB, 256, 0, stream>>>(rep_out, W000, b000, U, 1);
    gemm64_kernel<<<RB, 256, 0, stream>>>(U, W001, b001, V, 1);        // y00 hidden
    gemm64_kernel<<<RB, 256, 0, stream>>>(rep_out, W100, b100, U, 1);
    gemm64_kernel<<<RB, 256, 0, stream>>>(U, W101, b101, P, 1);        // y10 hidden

    // 8) final y
    y_kernel<<<RB, 256, 0, stream>>>(V, P, Wo0, bo0, Wo1, bo1, t, out_y);
}

// Round 2
// 774.778 us; speedup vs baseline: 1.0403x; 1.0403x over previous
//
#include <hip/hip_runtime.h>
#include <hip/hip_bf16.h>

#define N_NODES 10000
#define ROW4    2500          // float4 per adj row
#define CAP     64            // max nnz stored/row (Binomial tail past 64 ~1e-15)

// ---- workspace layout (float-element offsets; all 16B aligned) ----
#define OFF_CNT     0                         // int[10000]
#define OFF_COLSUM  10000                     // float[64]
#define OFF_COLS    10064                     // int[10000*64]
#define OFF_VALS    650064                    // float[10000*64]
#define OFF_SSRC    1290064                   // float[10000]
#define OFF_SDST    1300064                   // float[10000]
#define OFF_B1      1310064                   // float[10000*64]
#define OFF_B2      1950064
#define OFF_B3      2590064
#define OFF_B4      3230064
// total 3,870,064 floats = 15.5 MB

__device__ __forceinline__ float wave_sum(float v) {
    #pragma unroll
    for (int off = 32; off >= 1; off >>= 1) v += __shfl_xor(v, off, 64);
    return v;
}
__device__ __forceinline__ float wave_max(float v) {
    #pragma unroll
    for (int off = 32; off >= 1; off >>= 1) v = fmaxf(v, __shfl_xor(v, off, 64));
    return v;
}

// ---------------- K1: sparsify adj (the 400 MB streaming pass) ----------------
// grid 2500 blocks x 256; each block owns 4 rows (zeroes its own cnt first,
// so no separate zero kernel; block-local atomics only).
__global__ void k1_sparsify(const float4* __restrict__ adj4,
                            int* __restrict__ cnt,
                            int* __restrict__ cols,
                            float* __restrict__ vals,
                            float* __restrict__ colsum) {
    int tid = threadIdx.x;
    int row0 = blockIdx.x * 4;
    if (tid < 4) cnt[row0 + tid] = 0;
    if (blockIdx.x == 0 && tid < 64) colsum[tid] = 0.0f;   // consumed by K4
    __syncthreads();
    #pragma unroll
    for (int r = 0; r < 4; ++r) {
        int row = row0 + r;
        const float4* rp = adj4 + (size_t)row * ROW4;
        for (int idx = tid; idx < ROW4; idx += 256) {
            float4 v = rp[idx];
            float vv[4] = {v.x, v.y, v.z, v.w};
            #pragma unroll
            for (int l = 0; l < 4; ++l) {
                if (vv[l] != 0.0f) {
                    int pos = atomicAdd(&cnt[row], 1);
                    if (pos < CAP) {
                        cols[(size_t)row * CAP + pos] = idx * 4 + l;
                        vals[(size_t)row * CAP + pos] = vv[l];
                    }
                }
            }
        }
    }
}

// ---------------- K2: layer-1 dense GEMMs  P = x@Wg0, Q = x@Wt0 ----------------
// grid 1250 x 256; 8 rows/block; W staged in LDS (32 KB), x rows staged (4 KB).
// Inner loop reads xs via wave-uniform float4 (LDS broadcast) -> 160 ds_read
// instead of 256 per 128-K dot.
__global__ void k2_gemm128(const float* __restrict__ x,
                           const float* __restrict__ Wg0,
                           const float* __restrict__ Wt0,
                           float* __restrict__ P, float* __restrict__ Q) {
    __shared__ float Ws[128 * 64];
    __shared__ float xs[8 * 128];
    int tid = threadIdx.x;
    int row0 = blockIdx.x * 8;
    ((float4*)xs)[tid] = ((const float4*)(x + (size_t)row0 * 128))[tid];
    for (int i = tid; i < 2048; i += 256) ((float4*)Ws)[i] = ((const float4*)Wg0)[i];
    __syncthreads();
    int sub = tid >> 6, f = tid & 63;
    float accP[2];
    #pragma unroll
    for (int g = 0; g < 2; ++g) {
        const float* xr = xs + (g * 4 + sub) * 128;
        float acc = 0.0f;
        #pragma unroll 8
        for (int k = 0; k < 128; k += 4) {
            float4 xv = *(const float4*)(xr + k);
            acc += xv.x * Ws[(k + 0) * 64 + f] + xv.y * Ws[(k + 1) * 64 + f]
                 + xv.z * Ws[(k + 2) * 64 + f] + xv.w * Ws[(k + 3) * 64 + f];
        }
        accP[g] = acc;
    }
    #pragma unroll
    for (int g = 0; g < 2; ++g)
        P[(size_t)(row0 + g * 4 + sub) * 64 + f] = accP[g];
    __syncthreads();
    for (int i = tid; i < 2048; i += 256) ((float4*)Ws)[i] = ((const float4*)Wt0)[i];
    __syncthreads();
    #pragma unroll
    for (int g = 0; g < 2; ++g) {
        const float* xr = xs + (g * 4 + sub) * 128;
        float acc = 0.0f;
        #pragma unroll 8
        for (int k = 0; k < 128; k += 4) {
            float4 xv = *(const float4*)(xr + k);
            acc += xv.x * Ws[(k + 0) * 64 + f] + xv.y * Ws[(k + 1) * 64 + f]
                 + xv.z * Ws[(k + 2) * 64 + f] + xv.w * Ws[(k + 3) * 64 + f];
        }
        Q[(size_t)(row0 + g * 4 + sub) * 64 + f] = acc;
    }
}

// ---------------- K3: SpMM pair (layer-1 agg) + layer-2 dense GEMM pair --------
// layer-1 activations never touch global: SpMM result -> LDS -> gemm64 -> B3,B4.
__global__ void k3_agg_gemm(const int* __restrict__ cnt, const int* __restrict__ cols,
                            const float* __restrict__ vals,
                            const float* __restrict__ P, const float* __restrict__ Q,
                            const float* __restrict__ bg0, const float* __restrict__ bt0,
                            const float* __restrict__ Wg1, const float* __restrict__ Wt1,
                            float* __restrict__ P2, float* __restrict__ Q2) {
    __shared__ float Wa[64 * 64], Wb[64 * 64];
    __shared__ float ra[8 * 64], rb[8 * 64];
    int tid = threadIdx.x, row0 = blockIdx.x * 8, sub = tid >> 6, f = tid & 63;
    for (int i = tid; i < 1024; i += 256) {
        ((float4*)Wa)[i] = ((const float4*)Wg1)[i];
        ((float4*)Wb)[i] = ((const float4*)Wt1)[i];
    }
    float bo = bg0[f], bt = bt0[f];
    #pragma unroll
    for (int g = 0; g < 2; ++g) {
        int lr = g * 4 + sub, row = row0 + lr;
        int c = min(cnt[row], CAP);
        const int* cp = cols + (size_t)row * CAP;
        const float* vp = vals + (size_t)row * CAP;
        float aP = 0.0f, aQ = 0.0f;
        for (int p = 0; p < c; ++p) {
            int col = cp[p]; float v = vp[p];
            aP += v * P[(size_t)col * 64 + f];
            aQ += v * Q[(size_t)col * 64 + f];
        }
        ra[lr * 64 + f] = fmaxf(aP + bo, 0.0f);
        rb[lr * 64 + f] = fmaxf(aQ + bt, 0.0f);
    }
    __syncthreads();
    #pragma unroll
    for (int g = 0; g < 2; ++g) {
        int lr = g * 4 + sub, row = row0 + lr;
        const float* rra = ra + lr * 64;
        const float* rrb = rb + lr * 64;
        float aA = 0.0f, aB = 0.0f;
        #pragma unroll 8
        for (int k = 0; k < 64; k += 4) {
            float4 va = *(const float4*)(rra + k);
            float4 vb = *(const float4*)(rrb + k);
            aA += va.x * Wa[(k + 0) * 64 + f] + va.y * Wa[(k + 1) * 64 + f]
                + va.z * Wa[(k + 2) * 64 + f] + va.w * Wa[(k + 3) * 64 + f];
            aB += vb.x * Wb[(k + 0) * 64 + f] + vb.y * Wb[(k + 1) * 64 + f]
                + vb.z * Wb[(k + 2) * 64 + f] + vb.w * Wb[(k + 3) * 64 + f];
        }
        P2[(size_t)row * 64 + f] = aA;
        Q2[(size_t)row * 64 + f] = aB;
    }
}

// ---------------- K4: SpMM pair (layer-2 agg) + score + colsum + treatment -----
__global__ void k4_agg_score(const int* __restrict__ cnt, const int* __restrict__ cols,
                             const float* __restrict__ vals,
                             const float* __restrict__ P2, const float* __restrict__ Q2,
                             const float* __restrict__ bg1, const float* __restrict__ bt1,
                             const float* __restrict__ a,
                             const float* __restrict__ Wpp, const float* __restrict__ bpp,
                             const float* __restrict__ Wpp2, const float* __restrict__ bpp2,
                             float* __restrict__ rep_o, float* __restrict__ rep_t,
                             float* __restrict__ s_src, float* __restrict__ s_dst,
                             float* __restrict__ colsum, float* __restrict__ out_trt) {
    __shared__ float Wp[64 * 64];
    __shared__ float rts[8 * 64];
    int tid = threadIdx.x, row0 = blockIdx.x * 8, sub = tid >> 6, f = tid & 63;
    for (int i = tid; i < 1024; i += 256) ((float4*)Wp)[i] = ((const float4*)Wpp)[i];
    float bo = bg1[f], bt = bt1[f];
    float a0 = a[f], a1 = a[64 + f], a2 = a[128 + f], a3 = a[192 + f];
    #pragma unroll
    for (int g = 0; g < 2; ++g) {
        int lr = g * 4 + sub, row = row0 + lr;
        int c = min(cnt[row], CAP);
        const int* cp = cols + (size_t)row * CAP;
        const float* vp = vals + (size_t)row * CAP;
        float aO = 0.0f, aT = 0.0f;
        for (int p = 0; p < c; ++p) {
            int col = cp[p]; float v = vp[p];
            aO += v * P2[(size_t)col * 64 + f];
            aT += v * Q2[(size_t)col * 64 + f];
        }
        float vo = fmaxf(aO + bo, 0.0f);
        float vt = fmaxf(aT + bt, 0.0f);
        rep_o[(size_t)row * 64 + f] = vo;
        rep_t[(size_t)row * 64 + f] = vt;
        rts[lr * 64 + f] = vt;
        float ps = wave_sum(vo * a0 + vt * a1);
        float pd = wave_sum(vo * a2 + vt * a3);
        if (f == 0) { s_src[row] = ps; s_dst[row] = pd; }
    }
    __syncthreads();
    // one block-reduced atomic per feature for colsum
    if (sub == 0) {
        float cs = 0.0f;
        #pragma unroll
        for (int lr = 0; lr < 8; ++lr) cs += rts[lr * 64 + f];
        atomicAdd(&colsum[f], cs);
    }
    // treatment head: sigmoid((rep_t @ Wpp + bpp) @ Wpp2 + bpp2)
    float bp = bpp[f], w20 = Wpp2[f * 2 + 0], w21 = Wpp2[f * 2 + 1];
    #pragma unroll
    for (int g = 0; g < 2; ++g) {
        int lr = g * 4 + sub, row = row0 + lr;
        const float* rr = rts + lr * 64;
        float u = bp;
        #pragma unroll 8
        for (int k = 0; k < 64; k += 4) {
            float4 rv = *(const float4*)(rr + k);
            u += rv.x * Wp[(k + 0) * 64 + f] + rv.y * Wp[(k + 1) * 64 + f]
               + rv.z * Wp[(k + 2) * 64 + f] + rv.w * Wp[(k + 3) * 64 + f];
        }
        float p0 = wave_sum(u * w20);
        float p1 = wave_sum(u * w21);
        if (f == 0) {
            out_trt[(size_t)row * 2 + 0] = 1.0f / (1.0f + expf(-(p0 + bpp2[0])));
            out_trt[(size_t)row * 2 + 1] = 1.0f / (1.0f + expf(-(p1 + bpp2[1])));
        }
    }
}

// ---------------- K5: attention + outcome heads + select ----------------------
__global__ void k5_attn_heads(const int* __restrict__ cnt, const int* __restrict__ cols,
                              const float* __restrict__ s_src, const float* __restrict__ s_dst,
                              const float* __restrict__ colsum,
                              const float* __restrict__ rep_o, const float* __restrict__ rep_t,
                              const float* __restrict__ W000, const float* __restrict__ b000,
                              const float* __restrict__ W001, const float* __restrict__ b001,
                              const float* __restrict__ W100, const float* __restrict__ b100,
                              const float* __restrict__ W101, const float* __restrict__ b101,
                              const float* __restrict__ Wo0, const float* __restrict__ bo0,
                              const float* __restrict__ Wo1, const float* __restrict__ bo1,
                              const int* __restrict__ t,
                              float* __restrict__ out_y, float* __restrict__ out_rep) {
    __shared__ float WA[64 * 64], WB[64 * 64];
    __shared__ float reps[8 * 64], u0s[8 * 64], u1s[8 * 64];
    int tid = threadIdx.x, row0 = blockIdx.x * 8, sub = tid >> 6, f = tid & 63;
    for (int i = tid; i < 1024; i += 256) {
        ((float4*)WA)[i] = ((const float4*)W000)[i];
        ((float4*)WB)[i] = ((const float4*)W100)[i];
    }
    float csf = colsum[f];
    #pragma unroll
    for (int g = 0; g < 2; ++g) {
        int lr = g * 4 + sub, row = row0 + lr;
        int c = min(cnt[row], CAP);
        const int* cp = cols + (size_t)row * CAP;
        float ssrc = s_src[row];
        int   col_l = (f < c) ? cp[f] : 0;
        float s_l   = (f < c) ? ssrc + s_dst[col_l] : -1e30f;
        float m = fmaxf(wave_max(s_l), 0.0f);     // zeros of the dense row join the max
        float e_l = (f < c) ? expf(s_l - m) : 0.0f;
        float em = expf(-m);
        float Z = wave_sum(e_l) + (float)(N_NODES - c) * em;
        float acc = 0.0f;
        for (int p = 0; p < c; ++p) {
            float ep  = __shfl(e_l, p, 64);
            int  colp = __shfl(col_l, p, 64);
            acc += (ep - em) * rep_t[(size_t)colp * 64 + f];
        }
        float outv = (acc + em * csf) / Z + rep_o[(size_t)row * 64 + f];
        out_rep[(size_t)row * 64 + f] = outv;
        reps[lr * 64 + f] = outv;
    }
    __syncthreads();
    float bA = b000[f], bB = b100[f];
    #pragma unroll
    for (int g = 0; g < 2; ++g) {
        int lr = g * 4 + sub;
        const float* rr = reps + lr * 64;
        float u0 = bA, u1 = bB;
        #pragma unroll 8
        for (int k = 0; k < 64; k += 4) {
            float4 rv = *(const float4*)(rr + k);
            u0 += rv.x * WA[(k + 0) * 64 + f] + rv.y * WA[(k + 1) * 64 + f]
                + rv.z * WA[(k + 2) * 64 + f] + rv.w * WA[(k + 3) * 64 + f];
            u1 += rv.x * WB[(k + 0) * 64 + f] + rv.y * WB[(k + 1) * 64 + f]
                + rv.z * WB[(k + 2) * 64 + f] + rv.w * WB[(k + 3) * 64 + f];
        }
        u0s[lr * 64 + f] = fmaxf(u0, 0.0f);
        u1s[lr * 64 + f] = fmaxf(u1, 0.0f);
    }
    __syncthreads();
    for (int i = tid; i < 1024; i += 256) {
        ((float4*)WA)[i] = ((const float4*)W001)[i];
        ((float4*)WB)[i] = ((const float4*)W101)[i];
    }
    __syncthreads();
    float bC = b001[f], bD = b101[f], wo0 = Wo0[f], wo1 = Wo1[f];
    #pragma unroll
    for (int g = 0; g < 2; ++g) {
        int lr = g * 4 + sub, row = row0 + lr;
        const float* r0 = u0s + lr * 64;
        const float* r1 = u1s + lr * 64;
        float v0 = bC, v1 = bD;
        #pragma unroll 8
        for (int k = 0; k < 64; k += 4) {
            float4 a0 = *(const float4*)(r0 + k);
            float4 a1 = *(const float4*)(r1 + k);
            v0 += a0.x * WA[(k + 0) * 64 + f] + a0.y * WA[(k + 1) * 64 + f]
                + a0.z * WA[(k + 2) * 64 + f] + a0.w * WA[(k + 3) * 64 + f];
            v1 += a1.x * WB[(k + 0) * 64 + f] + a1.y * WB[(k + 1) * 64 + f]
                + a1.z * WB[(k + 2) * 64 + f] + a1.w * WB[(k + 3) * 64 + f];
        }
        float y0 = wave_sum(fmaxf(v0, 0.0f) * wo0);
        float y1 = wave_sum(fmaxf(v1, 0.0f) * wo1);
        if (f == 0)
            out_y[row] = (t[row] > 0) ? (y1 + bo1[0]) : (y0 + bo0[0]);
    }
}

// ---------------- launch ----------------

extern "C" void kernel_launch(void* const* d_in, const int* in_sizes, int n_in,
                              void* d_out, int out_size, void* d_ws, size_t ws_size,
                              hipStream_t stream) {
    const float* x    = (const float*)d_in[0];
    const float* adj  = (const float*)d_in[1];
    const int*   t    = (const int*)d_in[2];
    const float* Wg0  = (const float*)d_in[3];
    const float* bg0  = (const float*)d_in[4];
    const float* Wg1  = (const float*)d_in[5];
    const float* bg1  = (const float*)d_in[6];
    const float* Wt0  = (const float*)d_in[7];
    const float* bt0  = (const float*)d_in[8];
    const float* Wt1  = (const float*)d_in[9];
    const float* bt1  = (const float*)d_in[10];
    const float* W000 = (const float*)d_in[11];
    const float* b000 = (const float*)d_in[12];
    const float* W001 = (const float*)d_in[13];
    const float* b001 = (const float*)d_in[14];
    const float* W100 = (const float*)d_in[15];
    const float* b100 = (const float*)d_in[16];
    const float* W101 = (const float*)d_in[17];
    const float* b101 = (const float*)d_in[18];
    const float* Wo0  = (const float*)d_in[19];
    const float* bo0  = (const float*)d_in[20];
    const float* Wo1  = (const float*)d_in[21];
    const float* bo1  = (const float*)d_in[22];
    const float* Wpp  = (const float*)d_in[23];
    const float* bpp  = (const float*)d_in[24];
    const float* Wpp2 = (const float*)d_in[25];
    const float* bpp2 = (const float*)d_in[26];
    const float* a    = (const float*)d_in[27];

    float* ws = (float*)d_ws;
    int*   cnt    = (int*)(ws + OFF_CNT);
    float* colsum = ws + OFF_COLSUM;
    int*   cols   = (int*)(ws + OFF_COLS);
    float* vals   = ws + OFF_VALS;
    float* s_src  = ws + OFF_SSRC;
    float* s_dst  = ws + OFF_SDST;
    float* B1     = ws + OFF_B1;   // x@Wg0 -> (K4) rep_o
    float* B2     = ws + OFF_B2;   // x@Wt0 -> (K4) rep_t
    float* B3     = ws + OFF_B3;   // layer2 pre-agg outcome
    float* B4     = ws + OFF_B4;   // layer2 pre-agg treatment

    float* out_y   = (float*)d_out;                            // [N]
    float* out_rep = (float*)d_out + N_NODES;                  // [N,64]
    float* out_trt = (float*)d_out + N_NODES + N_NODES * 64;   // [N,2]

    k1_sparsify<<<2500, 256, 0, stream>>>((const float4*)adj, cnt, cols, vals, colsum);
    k2_gemm128<<<1250, 256, 0, stream>>>(x, Wg0, Wt0, B1, B2);
    k3_agg_gemm<<<1250, 256, 0, stream>>>(cnt, cols, vals, B1, B2, bg0, bt0, Wg1, Wt1, B3, B4);
    k4_agg_score<<<1250, 256, 0, stream>>>(cnt, cols, vals, B3, B4, bg1, bt1, a,
                                           Wpp, bpp, Wpp2, bpp2,
                                           B1, B2, s_src, s_dst, colsum, out_trt);
    k5_attn_heads<<<1250, 256, 0, stream>>>(cnt, cols, s_src, s_dst, colsum, B1, B2,
                                            W000, b000, W001, b001,
                                            W100, b100, W101, b101,
                                            Wo0, bo0, Wo1, bo1, t, out_y, out_rep);
}

// Round 3
// 690.400 us; speedup vs baseline: 1.1674x; 1.1222x over previous
//
#include <hip/hip_runtime.h>
#include <hip/hip_bf16.h>

#define N_NODES 10000
#define ROW4    2500          // float4 per adj row
#define CAP     64            // max nnz stored/row (Binomial(10000,0.002) tail past 64 ~1e-15)
#define GEMM_BLOCKS 1250      // k1 block-range split: [0,1250) gemm128, [1250,3750) sparsify

// ---- workspace layout (float-element offsets; all 16B aligned) ----
#define OFF_CNT     0                         // int[10000]
#define OFF_COLSUM  10000                     // float[64]
#define OFF_COLS    10064                     // int[10000*64]
#define OFF_VALS    650064                    // float[10000*64]
#define OFF_SSRC    1290064                   // float[10000]
#define OFF_SDST    1300064                   // float[10000]
#define OFF_B1      1310064                   // float[10000*64]
#define OFF_B2      1950064
#define OFF_B3      2590064
#define OFF_B4      3230064

__device__ __forceinline__ float wave_sum(float v) {
    #pragma unroll
    for (int off = 32; off >= 1; off >>= 1) v += __shfl_xor(v, off, 64);
    return v;
}
__device__ __forceinline__ float wave_max(float v) {
    #pragma unroll
    for (int off = 32; off >= 1; off >>= 1) v = fmaxf(v, __shfl_xor(v, off, 64));
    return v;
}

// ---------------- K1: sparsify (atomic-free) + layer-1 gemm128, fused ----------
// Blocks [0,GEMM_BLOCKS): P = x@Wg0, Q = x@Wt0 (8 rows/block, W via L1/L2).
// Blocks [GEMM_BLOCKS,3750): one wave per adj row; ballot/popc compaction,
// count kept in a scalar register -> zero atomics, no L2 round-trip stalls.
__global__ void k1_fused(const float4* __restrict__ adj4, const float* __restrict__ x,
                         const float* __restrict__ Wg0, const float* __restrict__ Wt0,
                         int* __restrict__ cnt, int* __restrict__ cols,
                         float* __restrict__ vals, float* __restrict__ colsum,
                         float* __restrict__ P, float* __restrict__ Q) {
    __shared__ float xs[8 * 128];
    int tid = threadIdx.x;
    if (blockIdx.x < GEMM_BLOCKS) {
        int row0 = blockIdx.x * 8;
        ((float4*)xs)[tid] = ((const float4*)(x + (size_t)row0 * 128))[tid];
        if (blockIdx.x == 0 && tid < 64) colsum[tid] = 0.0f;   // consumed by K3b
        __syncthreads();
        int sub = tid >> 6, f = tid & 63;
        #pragma unroll
        for (int g = 0; g < 2; ++g) {
            const float* xr = xs + (g * 4 + sub) * 128;
            float aP = 0.0f, aQ = 0.0f;
            #pragma unroll 8
            for (int k = 0; k < 128; k += 4) {
                float4 xv = *(const float4*)(xr + k);
                aP += xv.x * Wg0[(k + 0) * 64 + f] + xv.y * Wg0[(k + 1) * 64 + f]
                    + xv.z * Wg0[(k + 2) * 64 + f] + xv.w * Wg0[(k + 3) * 64 + f];
                aQ += xv.x * Wt0[(k + 0) * 64 + f] + xv.y * Wt0[(k + 1) * 64 + f]
                    + xv.z * Wt0[(k + 2) * 64 + f] + xv.w * Wt0[(k + 3) * 64 + f];
            }
            P[(size_t)(row0 + g * 4 + sub) * 64 + f] = aP;
            Q[(size_t)(row0 + g * 4 + sub) * 64 + f] = aQ;
        }
    } else {
        int lane = tid & 63, w = tid >> 6;
        int row = (blockIdx.x - GEMM_BLOCKS) * 4 + w;
        const float4* rp = adj4 + (size_t)row * ROW4;
        size_t base = (size_t)row * CAP;
        int count = 0;
        for (int it = 0; it < 40; ++it) {       // 40*64 = 2560 >= 2500
            int idx = it * 64 + lane;
            float4 v = make_float4(0.f, 0.f, 0.f, 0.f);
            if (idx < ROW4) v = rp[idx];
            float vv[4] = {v.x, v.y, v.z, v.w};
            bool any = (v.x != 0.f) | (v.y != 0.f) | (v.z != 0.f) | (v.w != 0.f);
            if (__ballot(any)) {                 // common case: whole wave zero -> 1 ballot
                #pragma unroll
                for (int l = 0; l < 4; ++l) {
                    unsigned long long b = __ballot(vv[l] != 0.f);
                    if (b) {
                        int pre = __popcll(b & ((1ull << lane) - 1ull));
                        if (vv[l] != 0.f) {
                            int pos = count + pre;
                            if (pos < CAP) {
                                cols[base + pos] = idx * 4 + l;
                                vals[base + pos] = vv[l];
                            }
                        }
                        count += (int)__popcll(b);
                    }
                }
            }
        }
        if (lane == 0) cnt[row] = min(count, CAP);
    }
}

// ---------------- K2: SpMM pair (layer-1 agg) + layer-2 gemm64 pair ------------
// Gather: (col,val) vector-loaded into lanes once, shfl-broadcast, unroll-8,
// 4 accumulators -> ~16 gathers in flight. Lanes >= c carry val 0 so the
// overshoot iterations self-mask. W via L1/L2; LDS only 4 KB -> 8 blocks/CU.
__global__ void k2_agg_gemm(const int* __restrict__ cnt, const int* __restrict__ cols,
                            const float* __restrict__ vals,
                            const float* __restrict__ P, const float* __restrict__ Q,
                            const float* __restrict__ bg0, const float* __restrict__ bt0,
                            const float* __restrict__ Wg1, const float* __restrict__ Wt1,
                            float* __restrict__ P2, float* __restrict__ Q2) {
    __shared__ float ra[8 * 64], rb[8 * 64];
    int tid = threadIdx.x, row0 = blockIdx.x * 8, sub = tid >> 6, f = tid & 63;
    float bo = bg0[f], bt = bt0[f];
    #pragma unroll
    for (int g = 0; g < 2; ++g) {
        int lr = g * 4 + sub, row = row0 + lr;
        int c = min(cnt[row], CAP);
        float v_l = 0.0f; int c_l = 0;
        if (f < c) { c_l = cols[(size_t)row * CAP + f]; v_l = vals[(size_t)row * CAP + f]; }
        float a0 = 0.f, a1 = 0.f, b0 = 0.f, b1 = 0.f;
        for (int p = 0; p < c; p += 8) {
            #pragma unroll
            for (int j = 0; j < 8; j += 2) {
                float vv0 = __shfl(v_l, p + j, 64);     int cc0 = __shfl(c_l, p + j, 64);
                float vv1 = __shfl(v_l, p + j + 1, 64); int cc1 = __shfl(c_l, p + j + 1, 64);
                a0 += vv0 * P[(size_t)cc0 * 64 + f];
                b0 += vv0 * Q[(size_t)cc0 * 64 + f];
                a1 += vv1 * P[(size_t)cc1 * 64 + f];
                b1 += vv1 * Q[(size_t)cc1 * 64 + f];
            }
        }
        ra[lr * 64 + f] = fmaxf(a0 + a1 + bo, 0.0f);
        rb[lr * 64 + f] = fmaxf(b0 + b1 + bt, 0.0f);
    }
    __syncthreads();
    #pragma unroll
    for (int g = 0; g < 2; ++g) {
        int lr = g * 4 + sub, row = row0 + lr;
        const float* rra = ra + lr * 64;
        const float* rrb = rb + lr * 64;
        float aA = 0.f, aB = 0.f;
        #pragma unroll 8
        for (int k = 0; k < 64; k += 4) {
            float4 va = *(const float4*)(rra + k);
            float4 vb = *(const float4*)(rrb + k);
            aA += va.x * Wg1[(k + 0) * 64 + f] + va.y * Wg1[(k + 1) * 64 + f]
                + va.z * Wg1[(k + 2) * 64 + f] + va.w * Wg1[(k + 3) * 64 + f];
            aB += vb.x * Wt1[(k + 0) * 64 + f] + vb.y * Wt1[(k + 1) * 64 + f]
                + vb.z * Wt1[(k + 2) * 64 + f] + vb.w * Wt1[(k + 3) * 64 + f];
        }
        P2[(size_t)row * 64 + f] = aA;
        Q2[(size_t)row * 64 + f] = aB;
    }
}

// ---------------- K3: SpMM pair (layer-2 agg) + score + colsum + treatment -----
__global__ void k3_agg_score(const int* __restrict__ cnt, const int* __restrict__ cols,
                             const float* __restrict__ vals,
                             const float* __restrict__ P2, const float* __restrict__ Q2,
                             const float* __restrict__ bg1, const float* __restrict__ bt1,
                             const float* __restrict__ a,
                             const float* __restrict__ Wpp, const float* __restrict__ bpp,
                             const float* __restrict__ Wpp2, const float* __restrict__ bpp2,
                             float* __restrict__ rep_o, float* __restrict__ rep_t,
                             float* __restrict__ s_src, float* __restrict__ s_dst,
                             float* __restrict__ colsum, float* __restrict__ out_trt) {
    __shared__ float rts[8 * 64];
    int tid = threadIdx.x, row0 = blockIdx.x * 8, sub = tid >> 6, f = tid & 63;
    float bo = bg1[f], bt = bt1[f];
    float a0c = a[f], a1c = a[64 + f], a2c = a[128 + f], a3c = a[192 + f];
    #pragma unroll
    for (int g = 0; g < 2; ++g) {
        int lr = g * 4 + sub, row = row0 + lr;
        int c = min(cnt[row], CAP);
        float v_l = 0.0f; int c_l = 0;
        if (f < c) { c_l = cols[(size_t)row * CAP + f]; v_l = vals[(size_t)row * CAP + f]; }
        float a0 = 0.f, a1 = 0.f, b0 = 0.f, b1 = 0.f;
        for (int p = 0; p < c; p += 8) {
            #pragma unroll
            for (int j = 0; j < 8; j += 2) {
                float vv0 = __shfl(v_l, p + j, 64);     int cc0 = __shfl(c_l, p + j, 64);
                float vv1 = __shfl(v_l, p + j + 1, 64); int cc1 = __shfl(c_l, p + j + 1, 64);
                a0 += vv0 * P2[(size_t)cc0 * 64 + f];
                b0 += vv0 * Q2[(size_t)cc0 * 64 + f];
                a1 += vv1 * P2[(size_t)cc1 * 64 + f];
                b1 += vv1 * Q2[(size_t)cc1 * 64 + f];
            }
        }
        float vo = fmaxf(a0 + a1 + bo, 0.0f);
        float vt = fmaxf(b0 + b1 + bt, 0.0f);
        rep_o[(size_t)row * 64 + f] = vo;
        rep_t[(size_t)row * 64 + f] = vt;
        rts[lr * 64 + f] = vt;
        float ps = wave_sum(vo * a0c + vt * a1c);
        float pd = wave_sum(vo * a2c + vt * a3c);
        if (f == 0) { s_src[row] = ps; s_dst[row] = pd; }
    }
    __syncthreads();
    if (sub == 0) {                       // one block-reduced atomic per feature
        float cs = 0.0f;
        #pragma unroll
        for (int lr = 0; lr < 8; ++lr) cs += rts[lr * 64 + f];
        atomicAdd(&colsum[f], cs);
    }
    float bp = bpp[f], w20 = Wpp2[f * 2 + 0], w21 = Wpp2[f * 2 + 1];
    #pragma unroll
    for (int g = 0; g < 2; ++g) {
        int lr = g * 4 + sub, row = row0 + lr;
        const float* rr = rts + lr * 64;
        float u = bp;
        #pragma unroll 8
        for (int k = 0; k < 64; k += 4) {
            float4 rv = *(const float4*)(rr + k);
            u += rv.x * Wpp[(k + 0) * 64 + f] + rv.y * Wpp[(k + 1) * 64 + f]
               + rv.z * Wpp[(k + 2) * 64 + f] + rv.w * Wpp[(k + 3) * 64 + f];
        }
        float p0 = wave_sum(u * w20);
        float p1 = wave_sum(u * w21);
        if (f == 0) {
            out_trt[(size_t)row * 2 + 0] = 1.0f / (1.0f + expf(-(p0 + bpp2[0])));
            out_trt[(size_t)row * 2 + 1] = 1.0f / (1.0f + expf(-(p1 + bpp2[1])));
        }
    }
}

// ---------------- K4: attention + outcome heads + select ----------------------
__global__ void k4_attn_heads(const int* __restrict__ cnt, const int* __restrict__ cols,
                              const float* __restrict__ s_src, const float* __restrict__ s_dst,
                              const float* __restrict__ colsum,
                              const float* __restrict__ rep_o, const float* __restrict__ rep_t,
                              const float* __restrict__ W000, const float* __restrict__ b000,
                              const float* __restrict__ W001, const float* __restrict__ b001,
                              const float* __restrict__ W100, const float* __restrict__ b100,
                              const float* __restrict__ W101, const float* __restrict__ b101,
                              const float* __restrict__ Wo0, const float* __restrict__ bo0,
                              const float* __restrict__ Wo1, const float* __restrict__ bo1,
                              const int* __restrict__ t,
                              float* __restrict__ out_y, float* __restrict__ out_rep) {
    __shared__ float reps[8 * 64], u0s[8 * 64], u1s[8 * 64];
    int tid = threadIdx.x, row0 = blockIdx.x * 8, sub = tid >> 6, f = tid & 63;
    float csf = colsum[f];
    #pragma unroll
    for (int g = 0; g < 2; ++g) {
        int lr = g * 4 + sub, row = row0 + lr;
        int c = min(cnt[row], CAP);
        float ssrc = s_src[row];
        int   col_l = (f < c) ? cols[(size_t)row * CAP + f] : 0;
        float s_l   = (f < c) ? ssrc + s_dst[col_l] : -1e30f;
        float m = fmaxf(wave_max(s_l), 0.0f);     // zeros of the dense row join the max
        float e_l = (f < c) ? expf(s_l - m) : 0.0f;
        float em = expf(-m);
        float Z = wave_sum(e_l) + (float)(N_NODES - c) * em;
        float g_l = (f < c) ? (e_l - em) : 0.0f;  // lanes >= c contribute 0 in overshoot
        float a0 = 0.f, a1 = 0.f, a2 = 0.f, a3 = 0.f;
        for (int p = 0; p < c; p += 8) {
            #pragma unroll
            for (int j = 0; j < 8; j += 4) {
                float g0 = __shfl(g_l, p + j + 0, 64); int c0 = __shfl(col_l, p + j + 0, 64);
                float g1 = __shfl(g_l, p + j + 1, 64); int c1 = __shfl(col_l, p + j + 1, 64);
                float g2 = __shfl(g_l, p + j + 2, 64); int c2 = __shfl(col_l, p + j + 2, 64);
                float g3 = __shfl(g_l, p + j + 3, 64); int c3 = __shfl(col_l, p + j + 3, 64);
                a0 += g0 * rep_t[(size_t)c0 * 64 + f];
                a1 += g1 * rep_t[(size_t)c1 * 64 + f];
                a2 += g2 * rep_t[(size_t)c2 * 64 + f];
                a3 += g3 * rep_t[(size_t)c3 * 64 + f];
            }
        }
        float outv = ((a0 + a1 + a2 + a3) + em * csf) / Z + rep_o[(size_t)row * 64 + f];
        out_rep[(size_t)row * 64 + f] = outv;
        reps[lr * 64 + f] = outv;
    }
    __syncthreads();
    float bA = b000[f], bB = b100[f];
    #pragma unroll
    for (int g = 0; g < 2; ++g) {
        int lr = g * 4 + sub;
        const float* rr = reps + lr * 64;
        float u0 = bA, u1 = bB;
        #pragma unroll 8
        for (int k = 0; k < 64; k += 4) {
            float4 rv = *(const float4*)(rr + k);
            u0 += rv.x * W000[(k + 0) * 64 + f] + rv.y * W000[(k + 1) * 64 + f]
                + rv.z * W000[(k + 2) * 64 + f] + rv.w * W000[(k + 3) * 64 + f];
            u1 += rv.x * W100[(k + 0) * 64 + f] + rv.y * W100[(k + 1) * 64 + f]
                + rv.z * W100[(k + 2) * 64 + f] + rv.w * W100[(k + 3) * 64 + f];
        }
        u0s[lr * 64 + f] = fmaxf(u0, 0.0f);
        u1s[lr * 64 + f] = fmaxf(u1, 0.0f);
    }
    __syncthreads();
    float bC = b001[f], bD = b101[f], wo0 = Wo0[f], wo1 = Wo1[f];
    #pragma unroll
    for (int g = 0; g < 2; ++g) {
        int lr = g * 4 + sub, row = row0 + lr;
        const float* r0 = u0s + lr * 64;
        const float* r1 = u1s + lr * 64;
        float v0 = bC, v1 = bD;
        #pragma unroll 8
        for (int k = 0; k < 64; k += 4) {
            float4 q0 = *(const float4*)(r0 + k);
            float4 q1 = *(const float4*)(r1 + k);
            v0 += q0.x * W001[(k + 0) * 64 + f] + q0.y * W001[(k + 1) * 64 + f]
                + q0.z * W001[(k + 2) * 64 + f] + q0.w * W001[(k + 3) * 64 + f];
            v1 += q1.x * W101[(k + 0) * 64 + f] + q1.y * W101[(k + 1) * 64 + f]
                + q1.z * W101[(k + 2) * 64 + f] + q1.w * W101[(k + 3) * 64 + f];
        }
        float y0 = wave_sum(fmaxf(v0, 0.0f) * wo0);
        float y1 = wave_sum(fmaxf(v1, 0.0f) * wo1);
        if (f == 0)
            out_y[row] = (t[row] > 0) ? (y1 + bo1[0]) : (y0 + bo0[0]);
    }
}

// ---------------- launch ----------------

extern "C" void kernel_launch(void* const* d_in, const int* in_sizes, int n_in,
                              void* d_out, int out_size, void* d_ws, size_t ws_size,
                              hipStream_t stream) {
    const float* x    = (const float*)d_in[0];
    const float* adj  = (const float*)d_in[1];
    const int*   t    = (const int*)d_in[2];
    const float* Wg0  = (const float*)d_in[3];
    const float* bg0  = (const float*)d_in[4];
    const float* Wg1  = (const float*)d_in[5];
    const float* bg1  = (const float*)d_in[6];
    const float* Wt0  = (const float*)d_in[7];
    const float* bt0  = (const float*)d_in[8];
    const float* Wt1  = (const float*)d_in[9];
    const float* bt1  = (const float*)d_in[10];
    const float* W000 = (const float*)d_in[11];
    const float* b000 = (const float*)d_in[12];
    const float* W001 = (const float*)d_in[13];
    const float* b001 = (const float*)d_in[14];
    const float* W100 = (const float*)d_in[15];
    const float* b100 = (const float*)d_in[16];
    const float* W101 = (const float*)d_in[17];
    const float* b101 = (const float*)d_in[18];
    const float* Wo0  = (const float*)d_in[19];
    const float* bo0  = (const float*)d_in[20];
    const float* Wo1  = (const float*)d_in[21];
    const float* bo1  = (const float*)d_in[22];
    const float* Wpp  = (const float*)d_in[23];
    const float* bpp  = (const float*)d_in[24];
    const float* Wpp2 = (const float*)d_in[25];
    const float* bpp2 = (const float*)d_in[26];
    const float* a    = (const float*)d_in[27];

    float* ws = (float*)d_ws;
    int*   cnt    = (int*)(ws + OFF_CNT);
    float* colsum = ws + OFF_COLSUM;
    int*   cols   = (int*)(ws + OFF_COLS);
    float* vals   = ws + OFF_VALS;
    float* s_src  = ws + OFF_SSRC;
    float* s_dst  = ws + OFF_SDST;
    float* B1     = ws + OFF_B1;   // x@Wg0 -> (K3) rep_o
    float* B2     = ws + OFF_B2;   // x@Wt0 -> (K3) rep_t
    float* B3     = ws + OFF_B3;   // layer2 pre-agg outcome
    float* B4     = ws + OFF_B4;   // layer2 pre-agg treatment

    float* out_y   = (float*)d_out;                            // [N]
    float* out_rep = (float*)d_out + N_NODES;                  // [N,64]
    float* out_trt = (float*)d_out + N_NODES + N_NODES * 64;   // [N,2]

    k1_fused<<<GEMM_BLOCKS + 2500, 256, 0, stream>>>((const float4*)adj, x, Wg0, Wt0,
                                                     cnt, cols, vals, colsum, B1, B2);
    k2_agg_gemm<<<1250, 256, 0, stream>>>(cnt, cols, vals, B1, B2, bg0, bt0, Wg1, Wt1, B3, B4);
    k3_agg_score<<<1250, 256, 0, stream>>>(cnt, cols, vals, B3, B4, bg1, bt1, a,
                                           Wpp, bpp, Wpp2, bpp2,
                                           B1, B2, s_src, s_dst, colsum, out_trt);
    k4_attn_heads<<<1250, 256, 0, stream>>>(cnt, cols, s_src, s_dst, colsum, B1, B2,
                                            W000, b000, W001, b001,
                                            W100, b100, W101, b101,
                                            Wo0, bo0, Wo1, bo1, t, out_y, out_rep);
}